// Round 4
// baseline (627.194 us; speedup 1.0000x reference)
//
#include <hip/hip_runtime.h>

#define N_NODES 100000
#define EDGES   1600000
#define CH      128
#define BN_EPS  1e-5f

#define BINS     782                  // ceil(100000 / 128)
#define CHUNKS   256                  // edge chunks for binning
#define CHUNK_E  (EDGES / CHUNKS)     // 6250, exact
#define HM       (BINS * CHUNKS)      // 200192 histogram cells
#define SCAN_NB  (HM / 256)           // 782, exact
#define NREP     64                   // BN-partial replicas

#define GCHUNKS  8                    // channel chunks (16 ch = 32 B/node each, 3.2 MB/chunk)
#define GBLKS    (N_NODES / 8)        // 12500 gather blocks per chunk (8 nodes/block)

typedef __attribute__((ext_vector_type(8))) __bf16 bf16x8;
typedef __attribute__((ext_vector_type(4))) __bf16 bf16x4;
typedef __attribute__((ext_vector_type(2))) __bf16 bf16x2;
typedef __attribute__((ext_vector_type(4))) float  f32x4;

// ---------------------------------------------------------------------------
// Pass 1: per-(bin, chunk) histogram.  histo_g[bin*CHUNKS + chunk]
// ---------------------------------------------------------------------------
__global__ __launch_bounds__(256) void histo_kernel(const int* __restrict__ dst,
                                                    int* __restrict__ histo_g) {
    __shared__ int h[BINS];
    int t = threadIdx.x;
    for (int b = t; b < BINS; b += 256) h[b] = 0;
    __syncthreads();
    int base = blockIdx.x * CHUNK_E;
    for (int i = t; i < CHUNK_E; i += 256)
        atomicAdd(&h[dst[base + i] >> 7], 1);
    __syncthreads();
    for (int b = t; b < BINS; b += 256)
        histo_g[b * CHUNKS + blockIdx.x] = h[b];
}

// ---------------------------------------------------------------------------
// exclusive scan over HM elements (block-local); blocksum holds block totals,
// scan2 turns them into exclusive block offsets. scan3 folded into consumers:
// full_scan[i] = scanned[i] + blocksum[i >> 8]   (CHUNKS == 256)
// ---------------------------------------------------------------------------
__global__ __launch_bounds__(256) void scan1(const int* __restrict__ in,
                                             int* __restrict__ scanned,
                                             int* __restrict__ blocksum) {
    __shared__ int sh[2][256];
    int t = threadIdx.x;
    int i = blockIdx.x * 256 + t;
    int v = in[i];
    sh[0][t] = v;
    __syncthreads();
    int pp = 0;
    #pragma unroll
    for (int off = 1; off < 256; off <<= 1) {
        int val = sh[pp][t] + ((t >= off) ? sh[pp][t - off] : 0);
        sh[1 - pp][t] = val;
        pp = 1 - pp;
        __syncthreads();
    }
    int incl = sh[pp][t];
    scanned[i] = incl - v;
    if (t == 255) blocksum[blockIdx.x] = incl;
}

__global__ __launch_bounds__(1024) void scan2(int* __restrict__ blocksum) {
    __shared__ int sh[2][1024];
    int t = threadIdx.x;
    int v = (t < SCAN_NB) ? blocksum[t] : 0;
    sh[0][t] = v;
    __syncthreads();
    int pp = 0;
    #pragma unroll
    for (int off = 1; off < 1024; off <<= 1) {
        int val = sh[pp][t] + ((t >= off) ? sh[pp][t - off] : 0);
        sh[1 - pp][t] = val;
        pp = 1 - pp;
        __syncthreads();
    }
    if (t < SCAN_NB) blocksum[t] = sh[pp][t] - v;
}

// ---------------------------------------------------------------------------
// Pass 2: placement.  binned[pos] = (src << 7) | (dst & 127)
// ---------------------------------------------------------------------------
__global__ __launch_bounds__(256) void place_kernel(const int* __restrict__ src,
                                                    const int* __restrict__ dst,
                                                    const int* __restrict__ scanned,
                                                    const int* __restrict__ blocksum,
                                                    int* __restrict__ binned) {
    __shared__ int cur[BINS];
    int t = threadIdx.x;
    for (int b = t; b < BINS; b += 256)
        cur[b] = scanned[b * CHUNKS + blockIdx.x] + blocksum[b];
    __syncthreads();
    int base = blockIdx.x * CHUNK_E;
    for (int i = t; i < CHUNK_E; i += 256) {
        int d = dst[base + i];
        int s = src[base + i];
        int pos = atomicAdd(&cur[d >> 7], 1);
        binned[pos] = (s << 7) | (d & 127);
    }
}

// ---------------------------------------------------------------------------
// Pass 3: per-bin counting sort -> full CSR (srcs sorted by dst), rowptr, dinv.
// ---------------------------------------------------------------------------
__global__ __launch_bounds__(256) void bin_csr(const int* __restrict__ binned,
                                               const int* __restrict__ scanned,
                                               const int* __restrict__ blocksum,
                                               int* __restrict__ srcs,
                                               int* __restrict__ rowptr,
                                               float* __restrict__ dinv) {
    __shared__ int cnt[128];
    __shared__ int sc[2][128];
    __shared__ int base[128];
    __shared__ int cur[128];
    const int t = threadIdx.x;
    const int bin = blockIdx.x;
    if (t < 128) { cnt[t] = 0; cur[t] = 0; }
    __syncthreads();
    const int beg = scanned[bin * CHUNKS] + blocksum[bin];
    const int end = (bin == BINS - 1) ? EDGES
                    : (scanned[(bin + 1) * CHUNKS] + blocksum[bin + 1]);
    for (int e = beg + t; e < end; e += 256)
        atomicAdd(&cnt[binned[e] & 127], 1);
    __syncthreads();
    if (t < 128) sc[0][t] = cnt[t];
    __syncthreads();
    int pp = 0;
    #pragma unroll
    for (int off = 1; off < 128; off <<= 1) {
        if (t < 128) sc[1 - pp][t] = sc[pp][t] + ((t >= off) ? sc[pp][t - off] : 0);
        pp = 1 - pp;
        __syncthreads();
    }
    if (t < 128) {
        base[t] = beg + sc[pp][t] - cnt[t];
        int n = (bin << 7) + t;
        if (n < N_NODES) {
            rowptr[n] = base[t];
            dinv[n] = rsqrtf((float)cnt[t] + 1.0f);
        }
    }
    if (bin == 0 && t == 0) rowptr[N_NODES] = EDGES;
    __syncthreads();
    for (int e = beg + t; e < end; e += 256) {
        int p = binned[e];
        int dl = p & 127;
        int pos = base[dl] + atomicAdd(&cur[dl], 1);
        srcs[pos] = p >> 7;
    }
}

// ---------------------------------------------------------------------------
// W transpose + bf16 convert for BOTH weights: Wt[n][k] = bf16(W[k][n]).
// Also zeroes the 64 B hs pad row (dummy-gather target for tail slots).
// ---------------------------------------------------------------------------
__global__ __launch_bounds__(256) void wtrans2(const float* __restrict__ W1,
                                               __bf16* __restrict__ Wt1,
                                               const float* __restrict__ W2,
                                               __bf16* __restrict__ Wt2,
                                               unsigned* __restrict__ hspad) {
    int b = blockIdx.x;
    if (b == 0 && threadIdx.x < 16) hspad[threadIdx.x] = 0u;
    const float* W = (b < 64) ? W1 : W2;
    __bf16* Wt = (b < 64) ? Wt1 : Wt2;
    int idx = (b & 63) * 256 + threadIdx.x;
    int n = idx >> 7, k = idx & 127;
    Wt[idx] = (__bf16)W[k * 128 + n];
}

// ---------------------------------------------------------------------------
// conv1 GEMM (fp32 A): hs2[ck][n][c] = bf16( dinv[n] * sum_k A[n][k] * W[k][c] )
// hs2 chunk-major: [8 chunks][N nodes][16 ch]  (ct == chunk index)
// ---------------------------------------------------------------------------
__global__ __launch_bounds__(256) void gemm_f32(const float* __restrict__ A,
                                                const __bf16* __restrict__ Wt,
                                                const float* __restrict__ dinv,
                                                __bf16* __restrict__ hs) {
    const int wave = threadIdx.x >> 6;
    const int rt = blockIdx.x * 4 + wave;
    if (rt >= N_NODES / 16) return;
    const int lane = threadIdx.x & 63;
    const int ln = lane & 15;
    const int quad = lane >> 4;
    const int arow = rt * 16 + ln;

    f32x4 acc[8];
    #pragma unroll
    for (int ct = 0; ct < 8; ++ct) acc[ct] = (f32x4){0.f, 0.f, 0.f, 0.f};

    #pragma unroll
    for (int k0 = 0; k0 < 128; k0 += 32) {
        const int k = k0 + quad * 8;
        float4 a0 = *(const float4*)(A + (size_t)arow * CH + k);
        float4 a1 = *(const float4*)(A + (size_t)arow * CH + k + 4);
        bf16x8 af;
        af[0] = (__bf16)a0.x; af[1] = (__bf16)a0.y;
        af[2] = (__bf16)a0.z; af[3] = (__bf16)a0.w;
        af[4] = (__bf16)a1.x; af[5] = (__bf16)a1.y;
        af[6] = (__bf16)a1.z; af[7] = (__bf16)a1.w;
        #pragma unroll
        for (int ct = 0; ct < 8; ++ct) {
            bf16x8 bfrag = *(const bf16x8*)(Wt + (size_t)(ct * 16 + ln) * CH + k);
            acc[ct] = __builtin_amdgcn_mfma_f32_16x16x32_bf16(af, bfrag, acc[ct], 0, 0, 0);
        }
    }

    #pragma unroll
    for (int r = 0; r < 4; ++r) {
        const int row_r = rt * 16 + quad * 4 + r;
        const float dr = dinv[row_r];
        #pragma unroll
        for (int ct = 0; ct < 8; ++ct)
            hs[((size_t)ct * N_NODES + row_r) * 16 + ln] = (__bf16)(acc[ct][r] * dr);
    }
}

// ---------------------------------------------------------------------------
// conv2 GEMM (bf16 A chunk-major + fused BN1-apply + relu)
// ---------------------------------------------------------------------------
__global__ __launch_bounds__(256) void gemm_bn(const __bf16* __restrict__ A,
                                               const __bf16* __restrict__ Wt,
                                               const float* __restrict__ dinv,
                                               const float* __restrict__ scale,
                                               const float* __restrict__ shift,
                                               __bf16* __restrict__ hs) {
    const int wave = threadIdx.x >> 6;
    const int rt = blockIdx.x * 4 + wave;
    if (rt >= N_NODES / 16) return;
    const int lane = threadIdx.x & 63;
    const int ln = lane & 15;
    const int quad = lane >> 4;
    const int arow = rt * 16 + ln;

    f32x4 acc[8];
    #pragma unroll
    for (int ct = 0; ct < 8; ++ct) acc[ct] = (f32x4){0.f, 0.f, 0.f, 0.f};

    #pragma unroll
    for (int k0 = 0; k0 < 128; k0 += 32) {
        const int k = k0 + quad * 8;                 // 0,8,16,...,120
        bf16x8 av = *(const bf16x8*)(A + ((size_t)(k >> 4) * N_NODES + arow) * 16 + (k & 15));
        bf16x8 af;
        #pragma unroll
        for (int j = 0; j < 8; ++j)
            af[j] = (__bf16)fmaxf(fmaf((float)av[j], scale[k + j], shift[k + j]), 0.f);
        #pragma unroll
        for (int ct = 0; ct < 8; ++ct) {
            bf16x8 bfrag = *(const bf16x8*)(Wt + (size_t)(ct * 16 + ln) * CH + k);
            acc[ct] = __builtin_amdgcn_mfma_f32_16x16x32_bf16(af, bfrag, acc[ct], 0, 0, 0);
        }
    }

    #pragma unroll
    for (int r = 0; r < 4; ++r) {
        const int row_r = rt * 16 + quad * 4 + r;
        const float dr = dinv[row_r];
        #pragma unroll
        for (int ct = 0; ct < 8; ++ct)
            hs[((size_t)ct * N_NODES + row_r) * 16 + ln] = (__bf16)(acc[ct][r] * dr);
    }
}

// ---------------------------------------------------------------------------
// XCD-pinned channel-chunked gather + fused BN stats.
// chunk = blockIdx & 7: blocks dispatch round-robin across the 8 XCDs, so
// each XCD processes exactly ONE 3.2 MB hs chunk -> chunk stays resident in
// that XCD's private 4 MB L2; gather is served at L2 bandwidth. srcs stream
// and agg stores are nontemporal so they don't evict the chunk.
// Wave = node-uniform (scalar rowptr/dinv); lane = 8 edge-slots x 8 cp dwords;
// 16 edges per iteration (4 independent loads in flight); tail slots read a
// zeroed 64 B pad row. 3-level shfl_xor slot reduce; 2 nodes per wave.
// ---------------------------------------------------------------------------
__global__ __launch_bounds__(256) void gather_xcd(const __bf16* __restrict__ hs2,
                                                  const int* __restrict__ srcs,
                                                  const int* __restrict__ rowptr,
                                                  const float* __restrict__ dinv,
                                                  __bf16* __restrict__ agg2,
                                                  float* __restrict__ gpart) {
    __shared__ float red[4][8][4];                 // [wave][cp][comp]
    const int wave = threadIdx.x >> 6;
    const int lane = threadIdx.x & 63;
    const int slot = lane >> 3;                    // edge slot 0..7
    const int cp   = lane & 7;                     // chan-pair dword 0..7
    const int chunk = blockIdx.x & 7;              // -> XCD id (round-robin)
    const int blk   = blockIdx.x >> 3;             // 0..12499
    const int nb = blk * 8 + wave * 2;
    const unsigned* hp = (const unsigned*)hs2 + (size_t)chunk * (N_NODES * 8);
    const int zidx = (GCHUNKS - chunk) * N_NODES;  // dummy node -> zero pad row

    unsigned resv = 0u;
    float s0 = 0.f, ss0 = 0.f, s1 = 0.f, ss1 = 0.f;

    #pragma unroll
    for (int it = 0; it < 2; ++it) {
        const int n = __builtin_amdgcn_readfirstlane(nb + it);
        const int beg = rowptr[n];
        const int deg = rowptr[n + 1] - beg;
        float ax = 0.f, ay = 0.f;
        int jp = beg + slot;                       // per-lane edge cursor
        int jrel = slot;
        for (int done = 0; done < deg; done += 16) {
            // two slot-steps' loads issued together (overread lands in histo_g)
            int ea = __builtin_nontemporal_load(srcs + jp);
            int eb = __builtin_nontemporal_load(srcs + jp + 8);
            ea = (jrel < deg) ? ea : zidx;
            eb = (jrel + 8 < deg) ? eb : zidx;
            unsigned va = hp[(ea << 3) + cp];
            unsigned vb = hp[(eb << 3) + cp];
            ax += __builtin_bit_cast(float, va << 16);
            ay += __builtin_bit_cast(float, va & 0xffff0000u);
            ax += __builtin_bit_cast(float, vb << 16);
            ay += __builtin_bit_cast(float, vb & 0xffff0000u);
            jp += 16; jrel += 16;
        }
        // reduce across slots (lane bits 3,4,5) -> all lanes hold full sum
        ax += __shfl_xor(ax, 8);  ay += __shfl_xor(ay, 8);
        ax += __shfl_xor(ax, 16); ay += __shfl_xor(ay, 16);
        ax += __shfl_xor(ax, 32); ay += __shfl_xor(ay, 32);
        // self row
        unsigned sv = hp[(n << 3) + cp];
        ax += __builtin_bit_cast(float, sv << 16);
        ay += __builtin_bit_cast(float, sv & 0xffff0000u);
        const float d = dinv[n];
        const float ox = ax * d, oy = ay * d;
        bf16x2 pk; pk[0] = (__bf16)ox; pk[1] = (__bf16)oy;
        resv = (slot == it) ? __builtin_bit_cast(unsigned, pk) : resv;
        s0 += ox; ss0 += ox * ox;
        s1 += oy; ss1 += oy * oy;
    }

    // store: slot 0/1 lanes hold nodes nb+0 / nb+1 -> 64 B nontemporal store
    if (slot < 2)
        __builtin_nontemporal_store(resv,
            (unsigned*)agg2 + (size_t)chunk * (N_NODES * 8) + (size_t)(nb + slot) * 8 + cp);

    // BN partials: identical across slot groups -> only slot 0 contributes
    if (slot == 0) {
        f32x4 rv; rv[0] = s0; rv[1] = ss0; rv[2] = s1; rv[3] = ss1;
        *(f32x4*)red[wave][cp] = rv;
    }
    __syncthreads();
    const int t = threadIdx.x;
    if (t < 32) {
        const int tcp = t >> 2, comp = t & 3;
        float acc = red[0][tcp][comp] + red[1][tcp][comp] +
                    red[2][tcp][comp] + red[3][tcp][comp];
        atomicAdd(&gpart[(blk & (NREP - 1)) * 256 + ((chunk * 8 + tcp) << 2) + comp], acc);
    }
}

// ---------------------------------------------------------------------------
// reduce 64 replicas -> mu/var -> scale/shift
// slot layout: gpart[r*256 + c2*4 + {0,1,2,3}] = {s_even, ss_even, s_odd, ss_odd}
// ---------------------------------------------------------------------------
__global__ void bn_final(const float* __restrict__ gpart,
                         const float* __restrict__ gamma,
                         const float* __restrict__ beta,
                         float* __restrict__ scale,
                         float* __restrict__ shift) {
    int c = threadIdx.x;                          // 128 threads
    int c2 = c >> 1, odd = c & 1;
    float s = 0.f, ss = 0.f;
    for (int r = 0; r < NREP; ++r) {
        s  += gpart[r * 256 + c2 * 4 + 2 * odd];
        ss += gpart[r * 256 + c2 * 4 + 2 * odd + 1];
    }
    const float invN = 1.0f / (float)N_NODES;
    float mu = s * invN;
    float var = ss * invN - mu * mu;
    float sc = gamma[c] * rsqrtf(var + BN_EPS);
    scale[c] = sc;
    shift[c] = beta[c] - mu * sc;
}

// ---------------------------------------------------------------------------
// final epilogue: out = relu(agg*scale + shift + x)   (agg bf16 chunk-major)
// ---------------------------------------------------------------------------
__global__ __launch_bounds__(256) void bn_apply_res_relu(const __bf16* __restrict__ v,
                                                         const float* __restrict__ scale,
                                                         const float* __restrict__ shift,
                                                         const float* __restrict__ xin,
                                                         float* __restrict__ outv) {
    int i = blockIdx.x * 256 + threadIdx.x;       // float4 index over N*32
    int n = i >> 5, cg = i & 31;
    bf16x4 a4 = *(const bf16x4*)(v + ((size_t)(cg >> 2) * N_NODES + n) * 16 + (cg & 3) * 4);
    float4 r = ((const float4*)xin)[i];
    float4 sc = ((const float4*)scale)[cg];
    float4 sh = ((const float4*)shift)[cg];
    float4 a;
    a.x = fmaxf(fmaf((float)a4[0], sc.x, sh.x) + r.x, 0.f);
    a.y = fmaxf(fmaf((float)a4[1], sc.y, sh.y) + r.y, 0.f);
    a.z = fmaxf(fmaf((float)a4[2], sc.z, sh.z) + r.z, 0.f);
    a.w = fmaxf(fmaf((float)a4[3], sc.w, sh.w) + r.w, 0.f);
    ((float4*)outv)[i] = a;
}

// ---------------------------------------------------------------------------
extern "C" void kernel_launch(void* const* d_in, const int* in_sizes, int n_in,
                              void* d_out, int out_size, void* d_ws, size_t ws_size,
                              hipStream_t stream) {
    const float* x      = (const float*)d_in[0];
    const float* W1     = (const float*)d_in[1];
    // b1/b2 cancel exactly inside BatchNorm (per-channel constant shift)
    const float* W2     = (const float*)d_in[3];
    const float* gamma2 = (const float*)d_in[5];
    const float* beta2  = (const float*)d_in[6];
    const int*   ei     = (const int*)d_in[7];    // [2, E] int32
    const int*   srcI   = ei;
    const int*   dstI   = ei + EDGES;
    float* out = (float*)d_out;

    char* ws = (char*)d_ws;
    __bf16*   agg      = (__bf16*)(ws);                    // 25.6 MB  [8][N][16] chunk-major
    __bf16*   hs       = (__bf16*)(ws + 25600000);         // 25.6 MB + 64 B zero pad
    unsigned* hspad    = (unsigned*)(ws + 51200000);       // 64 B pad (zeroed each launch)
    int*      binned   = (int*)   (ws + 51200128);         // 6.4 MB
    int*      srcs     = (int*)   (ws + 57600128);         // 6.4 MB (tail overread into histo: safe)
    int*      histo_g  = (int*)   (ws + 64000128);         // 800,768 B
    int*      scanned  = (int*)   (ws + 64800896);         // HM ints
    int*      blocksum = (int*)   (ws + 65601680);         // 3,128 B
    float*    dinv     = (float*) (ws + 65604864);         // 400 KB
    int*      rowptr   = (int*)   (ws + 66004864);         // 400,004 B
    __bf16*   Wt1      = (__bf16*)(ws + 66404928);         // 32 KB
    __bf16*   Wt2      = (__bf16*)(ws + 66437696);         // 32 KB
    float*    gpart    = (float*) (ws + 66470464);         // 64*256*4 = 64 KB
    float*    scale1   = (float*) (ws + 66536000);         // 4 x 128 f
    float*    shift1   = scale1 + 128;
    float*    scale2   = scale1 + 256;
    float*    shift2   = scale1 + 384;

    const int ELEM4_BLOCKS  = (N_NODES * 32) / 256;       // 12500
    const int GEMM_BLOCKS   = (N_NODES / 16 + 3) / 4;     // 1563
    const int GATHER_BLOCKS = GCHUNKS * GBLKS;            // 100000 (chunk = blockIdx & 7)

    // ---- binning + CSR (once, reused by both convs) ----
    histo_kernel<<<CHUNKS, 256, 0, stream>>>(dstI, histo_g);
    scan1<<<SCAN_NB, 256, 0, stream>>>(histo_g, scanned, blocksum);
    scan2<<<1, 1024, 0, stream>>>(blocksum);
    place_kernel<<<CHUNKS, 256, 0, stream>>>(srcI, dstI, scanned, blocksum, binned);
    bin_csr<<<BINS, 256, 0, stream>>>(binned, scanned, blocksum, srcs, rowptr, dinv);
    wtrans2<<<128, 256, 0, stream>>>(W1, Wt1, W2, Wt2, hspad);

    // ---- conv1 ----
    gemm_f32<<<GEMM_BLOCKS, 256, 0, stream>>>(x, Wt1, dinv, hs);
    hipMemsetAsync(gpart, 0, NREP * 256 * sizeof(float), stream);
    gather_xcd<<<GATHER_BLOCKS, 256, 0, stream>>>(hs, srcs, rowptr, dinv, agg, gpart);
    bn_final<<<1, 128, 0, stream>>>(gpart, gamma2, beta2, scale1, shift1);

    // ---- conv2 (BN1-apply + relu fused into A-fragment load) ----
    gemm_bn<<<GEMM_BLOCKS, 256, 0, stream>>>(agg, Wt2, dinv, scale1, shift1, hs);
    hipMemsetAsync(gpart, 0, NREP * 256 * sizeof(float), stream);
    gather_xcd<<<GATHER_BLOCKS, 256, 0, stream>>>(hs, srcs, rowptr, dinv, agg, gpart);
    bn_final<<<1, 128, 0, stream>>>(gpart, gamma2, beta2, scale2, shift2);
    bn_apply_res_relu<<<ELEM4_BLOCKS, 256, 0, stream>>>(agg, scale2, shift2, x, out);
}

// Round 5
// 378.014 us; speedup vs baseline: 1.6592x; 1.6592x over previous
//
#include <hip/hip_runtime.h>

#define N_NODES 100000
#define EDGES   1600000
#define CH      128
#define BN_EPS  1e-5f

#define BINS     782                  // ceil(100000 / 128)
#define CHUNKS   256                  // edge chunks for binning
#define CHUNK_E  (EDGES / CHUNKS)     // 6250, exact
#define HM       (BINS * CHUNKS)      // 200192 histogram cells
#define SCAN_NB  (HM / 256)           // 782, exact
#define NREP     64                   // BN-partial replicas

typedef __attribute__((ext_vector_type(8))) __bf16 bf16x8;
typedef __attribute__((ext_vector_type(4))) __bf16 bf16x4;
typedef __attribute__((ext_vector_type(2))) __bf16 bf16x2;
typedef __attribute__((ext_vector_type(4))) float  f32x4;

// ---------------------------------------------------------------------------
// Pass 1: per-(bin, chunk) histogram.  histo_g[bin*CHUNKS + chunk]
// ---------------------------------------------------------------------------
__global__ __launch_bounds__(256) void histo_kernel(const int* __restrict__ dst,
                                                    int* __restrict__ histo_g) {
    __shared__ int h[BINS];
    int t = threadIdx.x;
    for (int b = t; b < BINS; b += 256) h[b] = 0;
    __syncthreads();
    int base = blockIdx.x * CHUNK_E;
    for (int i = t; i < CHUNK_E; i += 256)
        atomicAdd(&h[dst[base + i] >> 7], 1);
    __syncthreads();
    for (int b = t; b < BINS; b += 256)
        histo_g[b * CHUNKS + blockIdx.x] = h[b];
}

// ---------------------------------------------------------------------------
// exclusive scan over HM elements (block-local); blocksum = block totals,
// scan2 -> exclusive block offsets. scan3 folded into consumers:
// full_scan[i] = scanned[i] + blocksum[i >> 8]   (CHUNKS == 256)
// ---------------------------------------------------------------------------
__global__ __launch_bounds__(256) void scan1(const int* __restrict__ in,
                                             int* __restrict__ scanned,
                                             int* __restrict__ blocksum) {
    __shared__ int sh[2][256];
    int t = threadIdx.x;
    int i = blockIdx.x * 256 + t;
    int v = in[i];
    sh[0][t] = v;
    __syncthreads();
    int pp = 0;
    #pragma unroll
    for (int off = 1; off < 256; off <<= 1) {
        int val = sh[pp][t] + ((t >= off) ? sh[pp][t - off] : 0);
        sh[1 - pp][t] = val;
        pp = 1 - pp;
        __syncthreads();
    }
    int incl = sh[pp][t];
    scanned[i] = incl - v;
    if (t == 255) blocksum[blockIdx.x] = incl;
}

__global__ __launch_bounds__(1024) void scan2(int* __restrict__ blocksum) {
    __shared__ int sh[2][1024];
    int t = threadIdx.x;
    int v = (t < SCAN_NB) ? blocksum[t] : 0;
    sh[0][t] = v;
    __syncthreads();
    int pp = 0;
    #pragma unroll
    for (int off = 1; off < 1024; off <<= 1) {
        int val = sh[pp][t] + ((t >= off) ? sh[pp][t - off] : 0);
        sh[1 - pp][t] = val;
        pp = 1 - pp;
        __syncthreads();
    }
    if (t < SCAN_NB) blocksum[t] = sh[pp][t] - v;
}

// ---------------------------------------------------------------------------
// Pass 2: placement.  binned[pos] = (src << 7) | (dst & 127)
// ---------------------------------------------------------------------------
__global__ __launch_bounds__(256) void place_kernel(const int* __restrict__ src,
                                                    const int* __restrict__ dst,
                                                    const int* __restrict__ scanned,
                                                    const int* __restrict__ blocksum,
                                                    int* __restrict__ binned) {
    __shared__ int cur[BINS];
    int t = threadIdx.x;
    for (int b = t; b < BINS; b += 256)
        cur[b] = scanned[b * CHUNKS + blockIdx.x] + blocksum[b];
    __syncthreads();
    int base = blockIdx.x * CHUNK_E;
    for (int i = t; i < CHUNK_E; i += 256) {
        int d = dst[base + i];
        int s = src[base + i];
        int pos = atomicAdd(&cur[d >> 7], 1);
        binned[pos] = (s << 7) | (d & 127);
    }
}

// ---------------------------------------------------------------------------
// Pass 3: per-bin counting sort -> full CSR (srcs sorted by dst), rowptr, dinv.
// ---------------------------------------------------------------------------
__global__ __launch_bounds__(256) void bin_csr(const int* __restrict__ binned,
                                               const int* __restrict__ scanned,
                                               const int* __restrict__ blocksum,
                                               int* __restrict__ srcs,
                                               int* __restrict__ rowptr,
                                               float* __restrict__ dinv) {
    __shared__ int cnt[128];
    __shared__ int sc[2][128];
    __shared__ int base[128];
    __shared__ int cur[128];
    const int t = threadIdx.x;
    const int bin = blockIdx.x;
    if (t < 128) { cnt[t] = 0; cur[t] = 0; }
    __syncthreads();
    const int beg = scanned[bin * CHUNKS] + blocksum[bin];
    const int end = (bin == BINS - 1) ? EDGES
                    : (scanned[(bin + 1) * CHUNKS] + blocksum[bin + 1]);
    for (int e = beg + t; e < end; e += 256)
        atomicAdd(&cnt[binned[e] & 127], 1);
    __syncthreads();
    if (t < 128) sc[0][t] = cnt[t];
    __syncthreads();
    int pp = 0;
    #pragma unroll
    for (int off = 1; off < 128; off <<= 1) {
        if (t < 128) sc[1 - pp][t] = sc[pp][t] + ((t >= off) ? sc[pp][t - off] : 0);
        pp = 1 - pp;
        __syncthreads();
    }
    if (t < 128) {
        base[t] = beg + sc[pp][t] - cnt[t];
        int n = (bin << 7) + t;
        if (n < N_NODES) {
            rowptr[n] = base[t];
            dinv[n] = rsqrtf((float)cnt[t] + 1.0f);
        }
    }
    if (bin == 0 && t == 0) rowptr[N_NODES] = EDGES;
    __syncthreads();
    for (int e = beg + t; e < end; e += 256) {
        int p = binned[e];
        int dl = p & 127;
        int pos = base[dl] + atomicAdd(&cur[dl], 1);
        srcs[pos] = p >> 7;
    }
}

// ---------------------------------------------------------------------------
// W transpose + bf16 convert for BOTH weights: Wt[n][k] = bf16(W[k][n]).
// Also zeroes the 256 B hs pad row (node index N_NODES, gather tail target).
// ---------------------------------------------------------------------------
__global__ __launch_bounds__(256) void wtrans2(const float* __restrict__ W1,
                                               __bf16* __restrict__ Wt1,
                                               const float* __restrict__ W2,
                                               __bf16* __restrict__ Wt2,
                                               unsigned* __restrict__ hspad) {
    int b = blockIdx.x;
    if (b == 0 && threadIdx.x < 64) hspad[threadIdx.x] = 0u;
    const float* W = (b < 64) ? W1 : W2;
    __bf16* Wt = (b < 64) ? Wt1 : Wt2;
    int idx = (b & 63) * 256 + threadIdx.x;
    int n = idx >> 7, k = idx & 127;
    Wt[idx] = (__bf16)W[k * 128 + n];
}

// ---------------------------------------------------------------------------
// conv1 GEMM (fp32 A): hs[n][c] = bf16( dinv[n] * sum_k A[n][k] * W[k][c] )
// ---------------------------------------------------------------------------
__global__ __launch_bounds__(256) void gemm_f32(const float* __restrict__ A,
                                                const __bf16* __restrict__ Wt,
                                                const float* __restrict__ dinv,
                                                __bf16* __restrict__ hs) {
    const int wave = threadIdx.x >> 6;
    const int rt = blockIdx.x * 4 + wave;
    if (rt >= N_NODES / 16) return;
    const int lane = threadIdx.x & 63;
    const int ln = lane & 15;
    const int quad = lane >> 4;
    const int arow = rt * 16 + ln;

    f32x4 acc[8];
    #pragma unroll
    for (int ct = 0; ct < 8; ++ct) acc[ct] = (f32x4){0.f, 0.f, 0.f, 0.f};

    #pragma unroll
    for (int k0 = 0; k0 < 128; k0 += 32) {
        const int k = k0 + quad * 8;
        float4 a0 = *(const float4*)(A + (size_t)arow * CH + k);
        float4 a1 = *(const float4*)(A + (size_t)arow * CH + k + 4);
        bf16x8 af;
        af[0] = (__bf16)a0.x; af[1] = (__bf16)a0.y;
        af[2] = (__bf16)a0.z; af[3] = (__bf16)a0.w;
        af[4] = (__bf16)a1.x; af[5] = (__bf16)a1.y;
        af[6] = (__bf16)a1.z; af[7] = (__bf16)a1.w;
        #pragma unroll
        for (int ct = 0; ct < 8; ++ct) {
            bf16x8 bfrag = *(const bf16x8*)(Wt + (size_t)(ct * 16 + ln) * CH + k);
            acc[ct] = __builtin_amdgcn_mfma_f32_16x16x32_bf16(af, bfrag, acc[ct], 0, 0, 0);
        }
    }

    #pragma unroll
    for (int r = 0; r < 4; ++r) {
        const int row_r = rt * 16 + quad * 4 + r;
        const float dr = dinv[row_r];
        __bf16* orow = hs + (size_t)row_r * CH + ln;
        #pragma unroll
        for (int ct = 0; ct < 8; ++ct)
            orow[ct * 16] = (__bf16)(acc[ct][r] * dr);
    }
}

// ---------------------------------------------------------------------------
// conv2 GEMM (bf16 A + fused BN1-apply + relu)
// ---------------------------------------------------------------------------
__global__ __launch_bounds__(256) void gemm_bn(const __bf16* __restrict__ A,
                                               const __bf16* __restrict__ Wt,
                                               const float* __restrict__ dinv,
                                               const float* __restrict__ scale,
                                               const float* __restrict__ shift,
                                               __bf16* __restrict__ hs) {
    const int wave = threadIdx.x >> 6;
    const int rt = blockIdx.x * 4 + wave;
    if (rt >= N_NODES / 16) return;
    const int lane = threadIdx.x & 63;
    const int ln = lane & 15;
    const int quad = lane >> 4;
    const int arow = rt * 16 + ln;

    f32x4 acc[8];
    #pragma unroll
    for (int ct = 0; ct < 8; ++ct) acc[ct] = (f32x4){0.f, 0.f, 0.f, 0.f};

    #pragma unroll
    for (int k0 = 0; k0 < 128; k0 += 32) {
        const int k = k0 + quad * 8;
        bf16x8 av = *(const bf16x8*)(A + (size_t)arow * CH + k);
        bf16x8 af;
        #pragma unroll
        for (int j = 0; j < 8; ++j)
            af[j] = (__bf16)fmaxf(fmaf((float)av[j], scale[k + j], shift[k + j]), 0.f);
        #pragma unroll
        for (int ct = 0; ct < 8; ++ct) {
            bf16x8 bfrag = *(const bf16x8*)(Wt + (size_t)(ct * 16 + ln) * CH + k);
            acc[ct] = __builtin_amdgcn_mfma_f32_16x16x32_bf16(af, bfrag, acc[ct], 0, 0, 0);
        }
    }

    #pragma unroll
    for (int r = 0; r < 4; ++r) {
        const int row_r = rt * 16 + quad * 4 + r;
        const float dr = dinv[row_r];
        __bf16* orow = hs + (size_t)row_r * CH + ln;
        #pragma unroll
        for (int ct = 0; ct < 8; ++ct)
            orow[ct * 16] = (__bf16)(acc[ct][r] * dr);
    }
}

// ---------------------------------------------------------------------------
// pull-gather (R0 structure) + fused BN stats, with the two nodes' edge
// loops INTERLEAVED: per iteration 8+8 guarded row-loads in flight (4 KB/wave,
// 2x the old MLP). Tail slots read a zeroed 256 B pad row (node N_NODES)
// instead of a scalar drain loop. Wave-uniform node -> scalar rowptr/srcs
// addressing; lane = channel pair (bf16x2 dword, 256 B coalesced row reads).
// Block = 4 waves x 2 nodes = 8 nodes; 12500 blocks.
// ---------------------------------------------------------------------------
__global__ __launch_bounds__(256) void gather_agg(const __bf16* __restrict__ hs,
                                                  const int* __restrict__ srcs,
                                                  const int* __restrict__ rowptr,
                                                  const float* __restrict__ dinv,
                                                  __bf16* __restrict__ agg,
                                                  float* __restrict__ gpart) {
    __shared__ float red[4][64][4];
    const int wave = threadIdx.x >> 6;
    const int c2 = threadIdx.x & 63;
    const bf16x2* hp = (const bf16x2*)hs;

    const int n0 = __builtin_amdgcn_readfirstlane(blockIdx.x * 8 + wave * 2);
    const int n1 = n0 + 1;
    const int b0 = rowptr[n0];
    const int e0 = rowptr[n0 + 1];
    const int e1 = rowptr[n1 + 1];
    const int b1 = e0;                             // CSR rows contiguous
    const int d0 = e0 - b0, d1 = e1 - b1;
    const int nt = (max(d0, d1) + 7) >> 3;

    bf16x2 sv0 = hp[(size_t)n0 * 64 + c2];         // self rows
    bf16x2 sv1 = hp[(size_t)n1 * 64 + c2];
    float ax0 = (float)sv0[0], ay0 = (float)sv0[1];
    float ax1 = (float)sv1[0], ay1 = (float)sv1[1];

    int j0 = b0, j1 = b1;
    for (int t = 0; t < nt; ++t) {
        int ea[8], eb[8];
        #pragma unroll
        for (int u = 0; u < 8; ++u) {
            int sa = srcs[j0 + u];                 // <=256 B overread -> binned/histo region, safe
            int sb = srcs[j1 + u];
            ea[u] = (j0 + u < e0) ? sa : N_NODES;  // pad row -> zeros
            eb[u] = (j1 + u < e1) ? sb : N_NODES;
        }
        bf16x2 va[8], vb[8];
        #pragma unroll
        for (int u = 0; u < 8; ++u) va[u] = hp[(size_t)ea[u] * 64 + c2];
        #pragma unroll
        for (int u = 0; u < 8; ++u) vb[u] = hp[(size_t)eb[u] * 64 + c2];
        ax0 += (((float)va[0][0] + (float)va[1][0]) + ((float)va[2][0] + (float)va[3][0]))
             + (((float)va[4][0] + (float)va[5][0]) + ((float)va[6][0] + (float)va[7][0]));
        ay0 += (((float)va[0][1] + (float)va[1][1]) + ((float)va[2][1] + (float)va[3][1]))
             + (((float)va[4][1] + (float)va[5][1]) + ((float)va[6][1] + (float)va[7][1]));
        ax1 += (((float)vb[0][0] + (float)vb[1][0]) + ((float)vb[2][0] + (float)vb[3][0]))
             + (((float)vb[4][0] + (float)vb[5][0]) + ((float)vb[6][0] + (float)vb[7][0]));
        ay1 += (((float)vb[0][1] + (float)vb[1][1]) + ((float)vb[2][1] + (float)vb[3][1]))
             + (((float)vb[4][1] + (float)vb[5][1]) + ((float)vb[6][1] + (float)vb[7][1]));
        j0 += 8; j1 += 8;
    }

    const float dd0 = dinv[n0], dd1 = dinv[n1];
    const float o0x = ax0 * dd0, o0y = ay0 * dd0;
    const float o1x = ax1 * dd1, o1y = ay1 * dd1;
    bf16x2 o0; o0[0] = (__bf16)o0x; o0[1] = (__bf16)o0y;
    bf16x2 o1; o1[0] = (__bf16)o1x; o1[1] = (__bf16)o1y;
    ((bf16x2*)agg)[(size_t)n0 * 64 + c2] = o0;
    ((bf16x2*)agg)[(size_t)n1 * 64 + c2] = o1;

    // BN partials: red[wave][c2] = {sum_even, sumsq_even, sum_odd, sumsq_odd}
    f32x4 rv;
    rv[0] = o0x + o1x; rv[1] = o0x * o0x + o1x * o1x;
    rv[2] = o0y + o1y; rv[3] = o0y * o0y + o1y * o1y;
    *(f32x4*)red[wave][c2] = rv;
    __syncthreads();
    const int t = threadIdx.x;                    // slot = (c2'<<2)|comp = t
    float v = red[0][t >> 2][t & 3] + red[1][t >> 2][t & 3] +
              red[2][t >> 2][t & 3] + red[3][t >> 2][t & 3];
    atomicAdd(&gpart[(blockIdx.x & (NREP - 1)) * 256 + t], v);
}

// ---------------------------------------------------------------------------
// reduce 64 replicas -> mu/var -> scale/shift
// slot layout: gpart[r*256 + c2*4 + {0,1,2,3}] = {s_even, ss_even, s_odd, ss_odd}
// ---------------------------------------------------------------------------
__global__ void bn_final(const float* __restrict__ gpart,
                         const float* __restrict__ gamma,
                         const float* __restrict__ beta,
                         float* __restrict__ scale,
                         float* __restrict__ shift) {
    int c = threadIdx.x;                          // 128 threads
    int c2 = c >> 1, odd = c & 1;
    float s = 0.f, ss = 0.f;
    for (int r = 0; r < NREP; ++r) {
        s  += gpart[r * 256 + c2 * 4 + 2 * odd];
        ss += gpart[r * 256 + c2 * 4 + 2 * odd + 1];
    }
    const float invN = 1.0f / (float)N_NODES;
    float mu = s * invN;
    float var = ss * invN - mu * mu;
    float sc = gamma[c] * rsqrtf(var + BN_EPS);
    scale[c] = sc;
    shift[c] = beta[c] - mu * sc;
}

// ---------------------------------------------------------------------------
// final epilogue: out = relu(agg*scale + shift + x)   (agg bf16, out fp32)
// ---------------------------------------------------------------------------
__global__ __launch_bounds__(256) void bn_apply_res_relu(const __bf16* __restrict__ v,
                                                         const float* __restrict__ scale,
                                                         const float* __restrict__ shift,
                                                         const float* __restrict__ xin,
                                                         float* __restrict__ outv) {
    int i = blockIdx.x * 256 + threadIdx.x;       // float4 index over N*32
    int cg = i & 31;
    bf16x4 a4 = ((const bf16x4*)v)[i];
    float4 r = ((const float4*)xin)[i];
    float4 sc = ((const float4*)scale)[cg];
    float4 sh = ((const float4*)shift)[cg];
    float4 a;
    a.x = fmaxf(fmaf((float)a4[0], sc.x, sh.x) + r.x, 0.f);
    a.y = fmaxf(fmaf((float)a4[1], sc.y, sh.y) + r.y, 0.f);
    a.z = fmaxf(fmaf((float)a4[2], sc.z, sh.z) + r.z, 0.f);
    a.w = fmaxf(fmaf((float)a4[3], sc.w, sh.w) + r.w, 0.f);
    ((float4*)outv)[i] = a;
}

// ---------------------------------------------------------------------------
extern "C" void kernel_launch(void* const* d_in, const int* in_sizes, int n_in,
                              void* d_out, int out_size, void* d_ws, size_t ws_size,
                              hipStream_t stream) {
    const float* x      = (const float*)d_in[0];
    const float* W1     = (const float*)d_in[1];
    // b1/b2 cancel exactly inside BatchNorm (per-channel constant shift)
    const float* W2     = (const float*)d_in[3];
    const float* gamma2 = (const float*)d_in[5];
    const float* beta2  = (const float*)d_in[6];
    const int*   ei     = (const int*)d_in[7];    // [2, E] int32
    const int*   srcI   = ei;
    const int*   dstI   = ei + EDGES;
    float* out = (float*)d_out;

    char* ws = (char*)d_ws;
    __bf16*   agg      = (__bf16*)(ws);                    // 25.6 MB
    __bf16*   hs       = (__bf16*)(ws + 25600000);         // 25.6 MB + 256 B pad row
    unsigned* hspad    = (unsigned*)(ws + 51200000);       // 256 B (node N_NODES)
    int*      binned   = (int*)   (ws + 51200256);         // 6.4 MB
    int*      srcs     = (int*)   (ws + 57600256);         // 6.4 MB (tail overread into histo: safe)
    int*      histo_g  = (int*)   (ws + 64000256);         // 800,768 B
    int*      scanned  = (int*)   (ws + 64801024);         // HM ints = 800,768 B
    int*      blocksum = (int*)   (ws + 65601792);         // 3,128 B
    float*    dinv     = (float*) (ws + 65604920);         // 400 KB
    int*      rowptr   = (int*)   (ws + 66004920);         // 400,004 B
    __bf16*   Wt1      = (__bf16*)(ws + 66404928);         // 32 KB
    __bf16*   Wt2      = (__bf16*)(ws + 66437696);         // 32 KB
    float*    gpart    = (float*) (ws + 66470464);         // 64*256*4 = 64 KB
    float*    scale1   = (float*) (ws + 66536000);         // 4 x 128 f
    float*    shift1   = scale1 + 128;
    float*    scale2   = scale1 + 256;
    float*    shift2   = scale1 + 384;

    const int ELEM4_BLOCKS  = (N_NODES * 32) / 256;       // 12500
    const int GEMM_BLOCKS   = (N_NODES / 16 + 3) / 4;     // 1563
    const int GATHER_BLOCKS = N_NODES / 8;                // 12500, exact

    // ---- binning + CSR (once, reused by both convs) ----
    histo_kernel<<<CHUNKS, 256, 0, stream>>>(dstI, histo_g);
    scan1<<<SCAN_NB, 256, 0, stream>>>(histo_g, scanned, blocksum);
    scan2<<<1, 1024, 0, stream>>>(blocksum);
    place_kernel<<<CHUNKS, 256, 0, stream>>>(srcI, dstI, scanned, blocksum, binned);
    bin_csr<<<BINS, 256, 0, stream>>>(binned, scanned, blocksum, srcs, rowptr, dinv);
    wtrans2<<<128, 256, 0, stream>>>(W1, Wt1, W2, Wt2, hspad);

    // ---- conv1 ----
    gemm_f32<<<GEMM_BLOCKS, 256, 0, stream>>>(x, Wt1, dinv, hs);
    hipMemsetAsync(gpart, 0, NREP * 256 * sizeof(float), stream);
    gather_agg<<<GATHER_BLOCKS, 256, 0, stream>>>(hs, srcs, rowptr, dinv, agg, gpart);
    bn_final<<<1, 128, 0, stream>>>(gpart, gamma2, beta2, scale1, shift1);

    // ---- conv2 (BN1-apply + relu fused into A-fragment load) ----
    gemm_bn<<<GEMM_BLOCKS, 256, 0, stream>>>(agg, Wt2, dinv, scale1, shift1, hs);
    hipMemsetAsync(gpart, 0, NREP * 256 * sizeof(float), stream);
    gather_agg<<<GATHER_BLOCKS, 256, 0, stream>>>(hs, srcs, rowptr, dinv, agg, gpart);
    bn_final<<<1, 128, 0, stream>>>(gpart, gamma2, beta2, scale2, shift2);
    bn_apply_res_relu<<<ELEM4_BLOCKS, 256, 0, stream>>>(agg, scale2, shift2, x, out);
}